// Round 1
// baseline (1369.177 us; speedup 1.0000x reference)
//
#include <hip/hip_runtime.h>
#include <math.h>

#define D_MODEL 1024
#define N_HEADS 16
#define D_K 64
#define B_SZ 64
#define S_LEN 2048

// ---------------- kernel 0: qh[b,n] = q[b,:] @ Wq[:,n] + bq[n] ----------------
// grid 256 = (64 b x 4 n-chunks), block 256
__global__ __launch_bounds__(256) void k_qh(const float* __restrict__ q,
                                            const float* __restrict__ Wq,
                                            const float* __restrict__ bq,
                                            float* __restrict__ qh) {
    int b = blockIdx.x >> 2;
    int nc = blockIdx.x & 3;
    int t = threadIdx.x;
    __shared__ float ql[D_MODEL];
    ((float4*)ql)[t] = ((const float4*)(q + (size_t)b * D_MODEL))[t];
    __syncthreads();
    int n = nc * 256 + t;
    const float* w = Wq + n;
    float acc = 0.f;
#pragma unroll 8
    for (int d = 0; d < D_MODEL; ++d) acc = fmaf(ql[d], w[(size_t)d * D_MODEL], acc);
    qh[(size_t)b * D_MODEL + n] = acc + bq[n];
}

// ---------------- kernel 1: qt[b,h,d] = (1/8) * sum_j qh[b,h*64+j] * Wk[d, h*64+j] ----------------
// grid 1024 = (b,h), block 256; thread covers d = t + 256p
__global__ __launch_bounds__(256) void k_qtil(const float* __restrict__ qh,
                                              const float* __restrict__ Wk,
                                              float* __restrict__ qt) {
    int b = blockIdx.x >> 4;
    int h = blockIdx.x & 15;
    int t = threadIdx.x;
    __shared__ float qhl[D_K];
    if (t < 16) ((float4*)qhl)[t] = ((const float4*)(qh + (size_t)b * D_MODEL + h * D_K))[t];
    __syncthreads();
#pragma unroll
    for (int p = 0; p < 4; ++p) {
        int d = p * 256 + t;
        const float* w = Wk + (size_t)d * D_MODEL + h * D_K;
        float acc = 0.f;
#pragma unroll
        for (int j4 = 0; j4 < 16; ++j4) {
            float4 w4 = ((const float4*)w)[j4];
            float4 q4 = ((const float4*)qhl)[j4];
            acc += w4.x * q4.x + w4.y * q4.y + w4.z * q4.z + w4.w * q4.w;
        }
        qt[((size_t)(b * N_HEADS + h)) * D_MODEL + d] = acc * 0.125f;
    }
}

// ---------------- kernel 2: scores[b,h,s] = k[b,s,:] . qt[b,h,:] ----------------
// grid 512 = (64 b x 8 s-tiles), block 256 = 4 waves.
// wave w -> heads 4w..4w+3 ; lane owns s = s0 + 64*i + lane (i<4). reg tile 4s x 4h.
#define ST 256
#define DC 32
#define KROW 36  // 32 + 4 pad: conflict-free b128 reads (quad = 9*row % 8)
__global__ __launch_bounds__(256) void k_scores(const float* __restrict__ k,
                                                const float* __restrict__ qt,
                                                float* __restrict__ sc) {
    __shared__ float kt[ST * KROW];          // 36 KB
    __shared__ float qtl[N_HEADS * DC];      // 2 KB
    int b = blockIdx.x >> 3;
    int st = blockIdx.x & 7;
    int t = threadIdx.x;
    int w = t >> 6, lane = t & 63;
    int s0 = st * ST;
    const float* kbase = k + ((size_t)b * S_LEN + s0) * D_MODEL;
    const float* qtbase = qt + (size_t)b * N_HEADS * D_MODEL;
    float acc[4][4] = {};
    for (int dc = 0; dc < D_MODEL; dc += DC) {
        // stage k tile: 256 s x 32 d ; 8 float4 per thread; 8 lanes per row (128B segs)
#pragma unroll
        for (int p = 0; p < 8; ++p) {
            int idx = t + 256 * p;
            int s = idx >> 3, d4 = idx & 7;
            float4 v4 = *(const float4*)(kbase + (size_t)s * D_MODEL + dc + 4 * d4);
            *(float4*)(kt + s * KROW + 4 * d4) = v4;
        }
        // stage qt tile: 16 h x 32 d
        if (t < 128) {
            int h = t >> 3, d4 = t & 7;
            *(float4*)(qtl + h * DC + 4 * d4) =
                *(const float4*)(qtbase + (size_t)h * D_MODEL + dc + 4 * d4);
        }
        __syncthreads();
#pragma unroll
        for (int d4 = 0; d4 < DC / 4; ++d4) {
            float4 qv[4], kv[4];
#pragma unroll
            for (int j = 0; j < 4; ++j) qv[j] = *(const float4*)(qtl + (4 * w + j) * DC + 4 * d4);
#pragma unroll
            for (int i = 0; i < 4; ++i) kv[i] = *(const float4*)(kt + (64 * i + lane) * KROW + 4 * d4);
#pragma unroll
            for (int i = 0; i < 4; ++i)
#pragma unroll
                for (int j = 0; j < 4; ++j)
                    acc[i][j] = fmaf(kv[i].x, qv[j].x,
                                fmaf(kv[i].y, qv[j].y,
                                fmaf(kv[i].z, qv[j].z,
                                fmaf(kv[i].w, qv[j].w, acc[i][j]))));
        }
        __syncthreads();
    }
#pragma unroll
    for (int j = 0; j < 4; ++j)
#pragma unroll
        for (int i = 0; i < 4; ++i)
            sc[((size_t)(b * N_HEADS + 4 * w + j)) * S_LEN + s0 + 64 * i + lane] = acc[i][j];
}

// ---------------- kernel 3: softmax in-place over s (row = b*16+h) ----------------
__global__ __launch_bounds__(256) void k_softmax(float* __restrict__ sc) {
    int row = blockIdx.x;
    int t = threadIdx.x;
    float4* p = (float4*)(sc + (size_t)row * S_LEN);
    float4 x0 = p[t];
    float4 x1 = p[t + 256];
    float m = fmaxf(fmaxf(fmaxf(x0.x, x0.y), fmaxf(x0.z, x0.w)),
                    fmaxf(fmaxf(x1.x, x1.y), fmaxf(x1.z, x1.w)));
#pragma unroll
    for (int o = 32; o; o >>= 1) m = fmaxf(m, __shfl_xor(m, o, 64));
    __shared__ float redm[4], reds[4];
    int w = t >> 6, lane = t & 63;
    if (lane == 0) redm[w] = m;
    __syncthreads();
    m = fmaxf(fmaxf(redm[0], redm[1]), fmaxf(redm[2], redm[3]));
    x0.x = __expf(x0.x - m); x0.y = __expf(x0.y - m);
    x0.z = __expf(x0.z - m); x0.w = __expf(x0.w - m);
    x1.x = __expf(x1.x - m); x1.y = __expf(x1.y - m);
    x1.z = __expf(x1.z - m); x1.w = __expf(x1.w - m);
    float s = x0.x + x0.y + x0.z + x0.w + x1.x + x1.y + x1.z + x1.w;
#pragma unroll
    for (int o = 32; o; o >>= 1) s += __shfl_xor(s, o, 64);
    if (lane == 0) reds[w] = s;
    __syncthreads();
    s = reds[0] + reds[1] + reds[2] + reds[3];
    float inv = 1.0f / s;
    x0.x *= inv; x0.y *= inv; x0.z *= inv; x0.w *= inv;
    x1.x *= inv; x1.y *= inv; x1.z *= inv; x1.w *= inv;
    p[t] = x0;
    p[t + 256] = x1;
}

// ---------------- kernel 4: part[ch,b,h,d] = sum_{s in chunk} attn[b,h,s] * v[b,s,d] ----------------
// grid 512 = (64 b x 8 s-chunks), block 256; thread owns d-float4 = 4t..4t+3; 16 head accums.
__global__ __launch_bounds__(256) void k_av(const float* __restrict__ v,
                                            const float* __restrict__ sc,
                                            float* __restrict__ part) {
    int b = blockIdx.x >> 3;
    int ch = blockIdx.x & 7;
    int t = threadIdx.x;
    int s0 = ch * 256;
    __shared__ float al[N_HEADS * 256];  // [h][s], 16 KB
#pragma unroll
    for (int p = 0; p < 4; ++p) {
        int idx = t + 256 * p;
        int h = idx >> 6, s4 = idx & 63;
        *(float4*)(al + h * 256 + 4 * s4) =
            *(const float4*)(sc + ((size_t)(b * N_HEADS + h)) * S_LEN + s0 + 4 * s4);
    }
    __syncthreads();
    float4 acc[N_HEADS];
#pragma unroll
    for (int h = 0; h < N_HEADS; ++h) acc[h] = make_float4(0.f, 0.f, 0.f, 0.f);
    const float* vbase = v + ((size_t)b * S_LEN + s0) * D_MODEL + 4 * t;
    for (int sg = 0; sg < 64; ++sg) {
        float4 v0 = *(const float4*)(vbase + (size_t)(4 * sg + 0) * D_MODEL);
        float4 v1 = *(const float4*)(vbase + (size_t)(4 * sg + 1) * D_MODEL);
        float4 v2 = *(const float4*)(vbase + (size_t)(4 * sg + 2) * D_MODEL);
        float4 v3 = *(const float4*)(vbase + (size_t)(4 * sg + 3) * D_MODEL);
#pragma unroll
        for (int h = 0; h < N_HEADS; ++h) {
            float4 a4 = *(const float4*)(al + h * 256 + 4 * sg);  // broadcast read
            acc[h].x = fmaf(a4.x, v0.x, fmaf(a4.y, v1.x, fmaf(a4.z, v2.x, fmaf(a4.w, v3.x, acc[h].x))));
            acc[h].y = fmaf(a4.x, v0.y, fmaf(a4.y, v1.y, fmaf(a4.z, v2.y, fmaf(a4.w, v3.y, acc[h].y))));
            acc[h].z = fmaf(a4.x, v0.z, fmaf(a4.y, v1.z, fmaf(a4.z, v2.z, fmaf(a4.w, v3.z, acc[h].z))));
            acc[h].w = fmaf(a4.x, v0.w, fmaf(a4.y, v1.w, fmaf(a4.z, v2.w, fmaf(a4.w, v3.w, acc[h].w))));
        }
    }
#pragma unroll
    for (int h = 0; h < N_HEADS; ++h)
        *(float4*)(part + (((size_t)ch * B_SZ + b) * N_HEADS + h) * D_MODEL + 4 * t) = acc[h];
}

// ---------------- kernel 5: cc[b, h*64+j] = sum_d vt[b,h,d]*Wv[d,h*64+j] + bv ----------------
// grid 1024 = (b,h), block 64 (1 wave); vt = sum of 8 partials, staged in LDS
__global__ __launch_bounds__(64) void k_cc(const float* __restrict__ part,
                                           const float* __restrict__ Wv,
                                           const float* __restrict__ bv,
                                           float* __restrict__ cc) {
    int b = blockIdx.x >> 4, h = blockIdx.x & 15;
    int lane = threadIdx.x;
    __shared__ float vt[D_MODEL];
#pragma unroll
    for (int p = 0; p < 4; ++p) {
        int i4 = lane + 64 * p;
        float4 s = make_float4(0.f, 0.f, 0.f, 0.f);
#pragma unroll
        for (int ch = 0; ch < 8; ++ch) {
            float4 x = *(const float4*)(part + (((size_t)ch * B_SZ + b) * N_HEADS + h) * D_MODEL + 4 * i4);
            s.x += x.x; s.y += x.y; s.z += x.z; s.w += x.w;
        }
        *(float4*)(vt + 4 * i4) = s;
    }
    __syncthreads();
    const float* w = Wv + h * D_K + lane;
    float acc = 0.f;
#pragma unroll 8
    for (int d = 0; d < D_MODEL; ++d) acc = fmaf(vt[d], w[(size_t)d * D_MODEL], acc);
    cc[(size_t)b * D_MODEL + h * D_K + lane] = acc + bv[h * D_K + lane];
}

// ---------------- kernel 6: out[b,n] = relu(cc[b,:] @ Wo[:,n] + bo[n]) ----------------
// grid 256 = (64 b x 4 n-chunks), block 256
__global__ __launch_bounds__(256) void k_out(const float* __restrict__ cc,
                                             const float* __restrict__ Wo,
                                             const float* __restrict__ bo,
                                             float* __restrict__ out) {
    int b = blockIdx.x >> 2, nc = blockIdx.x & 3;
    int t = threadIdx.x;
    __shared__ float cl[D_MODEL];
    ((float4*)cl)[t] = ((const float4*)(cc + (size_t)b * D_MODEL))[t];
    __syncthreads();
    int n = nc * 256 + t;
    const float* w = Wo + n;
    float acc = 0.f;
#pragma unroll 8
    for (int m = 0; m < D_MODEL; ++m) acc = fmaf(cl[m], w[(size_t)m * D_MODEL], acc);
    float r = acc + bo[n];
    out[(size_t)b * D_MODEL + n] = r > 0.f ? r : 0.f;
}

extern "C" void kernel_launch(void* const* d_in, const int* in_sizes, int n_in,
                              void* d_out, int out_size, void* d_ws, size_t ws_size,
                              hipStream_t stream) {
    const float* q  = (const float*)d_in[0];
    const float* k  = (const float*)d_in[1];
    const float* v  = (const float*)d_in[2];
    const float* Wq = (const float*)d_in[3];
    const float* bq = (const float*)d_in[4];
    const float* Wk = (const float*)d_in[5];
    // d_in[6] = bk: unused — softmax is shift-invariant, qh.bk is constant per (b,h) row
    const float* Wv = (const float*)d_in[7];
    const float* bv = (const float*)d_in[8];
    const float* Wo = (const float*)d_in[9];
    const float* bo = (const float*)d_in[10];
    float* out = (float*)d_out;

    float* ws = (float*)d_ws;
    float* qh   = ws;                       // 65536
    float* qt   = qh + 65536;               // 1048576
    float* sc   = qt + 1048576;             // 2097152
    float* part = sc + 2097152;             // 8388608
    float* cc   = part + 8388608;           // 65536   (total ~46.7 MB)

    k_qh<<<256, 256, 0, stream>>>(q, Wq, bq, qh);
    k_qtil<<<1024, 256, 0, stream>>>(qh, Wk, qt);
    k_scores<<<512, 256, 0, stream>>>(k, qt, sc);
    k_softmax<<<1024, 256, 0, stream>>>(sc);
    k_av<<<512, 256, 0, stream>>>(v, sc, part);
    k_cc<<<1024, 64, 0, stream>>>(part, Wv, bv, cc);
    k_out<<<256, 256, 0, stream>>>(cc, Wo, bo, out);
}